// Round 5
// baseline (244.715 us; speedup 1.0000x reference)
//
#include <hip/hip_runtime.h>
#include <hip/hip_bf16.h>

typedef unsigned short u16;
typedef unsigned int   u32;
typedef short  s16x8  __attribute__((ext_vector_type(8)));
typedef float  f32x16 __attribute__((ext_vector_type(16)));

__device__ __forceinline__ u16 f2bf(float f) {
    union { u32 i; float f; } x; x.f = f;
    u32 r = x.i + 0x7fffu + ((x.i >> 16) & 1u);
    return (u16)(r >> 16);
}
// packed fp32x2 -> bf16x2 (hardware v_cvt on gfx950 via HIP intrinsic)
__device__ __forceinline__ u32 pk_bf16(float a, float b) {
    __hip_bfloat162 h = __float22bfloat162_rn(make_float2(a, b));
    union { __hip_bfloat162 h; u32 u; } c; c.h = h; return c.u;
}

#define PD 512

// ======================= Projection GEMM (MFMA) =======================
// z=0: Q = query @ Wq^T -> Qo bf16, pre-scaled by (1/sqrt(512))*log2(e)
// z=1: K = keys  @ Wk^T -> Ko bf16
// z=2: V^T = Wv @ keys^T -> Vt[(b*8+h)*64+dh][2048] bf16
__global__ __launch_bounds__(256) void proj_mfma(
    const float* __restrict__ query, const float* __restrict__ keys,
    const float* __restrict__ Wq, const float* __restrict__ Wk, const float* __restrict__ Wv,
    u16* __restrict__ Qo, u16* __restrict__ Ko, u16* __restrict__ Vt)
{
    const int z = blockIdx.z;
    const float* __restrict__ X = (z == 0) ? query : keys;
    const float* __restrict__ W = (z == 0) ? Wq : ((z == 1) ? Wk : Wv);
    const int bx = blockIdx.x;   // 0..63 token-tile (128)
    const int by = blockIdx.y;   // 0..3  outdim-tile (128)

    const float* __restrict__ Amat = (z < 2) ? X : W;
    const float* __restrict__ Bmat = (z < 2) ? W : X;
    const int a0 = ((z < 2) ? bx : by) * 128;
    const int b0 = ((z < 2) ? by : bx) * 128;

    __shared__ u16 As[128][40];   // [row][k], +8 pad: 16B-aligned rows, <=4-way conflicts
    __shared__ u16 Bs[128][40];

    const int tid  = threadIdx.x;
    const int wave = tid >> 6, lane = tid & 63;
    const int wm = wave >> 1, wn = wave & 1;
    const int l31 = lane & 31, lh = lane >> 5;

    const int srow = tid >> 1;         // 0..127 staging row
    const int sk   = (tid & 1) * 16;   // 0/16   staging k-offset

    f32x16 acc[2][2];
    #pragma unroll
    for (int i = 0; i < 2; ++i)
        #pragma unroll
        for (int j = 0; j < 2; ++j)
            #pragma unroll
            for (int r = 0; r < 16; ++r) acc[i][j][r] = 0.f;

    for (int k0 = 0; k0 < PD; k0 += 32) {
        __syncthreads();
        {
            const float* ap = Amat + (size_t)(a0 + srow) * PD + k0 + sk;
            const float* bp = Bmat + (size_t)(b0 + srow) * PD + k0 + sk;
            u32 aw[8], bw[8];
            #pragma unroll
            for (int i = 0; i < 4; ++i) {
                float4 av = *(const float4*)(ap + 4*i);
                float4 bv = *(const float4*)(bp + 4*i);
                aw[2*i]   = pk_bf16(av.x, av.y);
                aw[2*i+1] = pk_bf16(av.z, av.w);
                bw[2*i]   = pk_bf16(bv.x, bv.y);
                bw[2*i+1] = pk_bf16(bv.z, bv.w);
            }
            *(uint4*)&As[srow][sk]     = *(uint4*)&aw[0];
            *(uint4*)&As[srow][sk + 8] = *(uint4*)&aw[4];
            *(uint4*)&Bs[srow][sk]     = *(uint4*)&bw[0];
            *(uint4*)&Bs[srow][sk + 8] = *(uint4*)&bw[4];
        }
        __syncthreads();

        #pragma unroll
        for (int ks = 0; ks < 2; ++ks) {
            s16x8 af[2], bfr[2];
            #pragma unroll
            for (int mf = 0; mf < 2; ++mf) {
                uint4 v = *(uint4*)&As[wm*64 + mf*32 + l31][ks*16 + lh*8];
                af[mf] = *(s16x8*)&v;
            }
            #pragma unroll
            for (int nf = 0; nf < 2; ++nf) {
                uint4 v = *(uint4*)&Bs[wn*64 + nf*32 + l31][ks*16 + lh*8];
                bfr[nf] = *(s16x8*)&v;
            }
            #pragma unroll
            for (int mf = 0; mf < 2; ++mf)
                #pragma unroll
                for (int nf = 0; nf < 2; ++nf)
                    acc[mf][nf] = __builtin_amdgcn_mfma_f32_32x32x16_bf16(
                        af[mf], bfr[nf], acc[mf][nf], 0, 0, 0);
        }
    }

    // C/D layout: col=lane&31, row=(reg&3)+8*(reg>>2)+4*(lane>>5)
    // Q gets (1/sqrt(512)) * log2(e) so attention softmax can use raw exp2.
    const float osc = (z == 0) ? (0.044194173824159216f * 1.4426950408889634f) : 1.0f;
    u16* __restrict__ O = (z == 0) ? Qo : Ko;
    #pragma unroll
    for (int mf = 0; mf < 2; ++mf)
        #pragma unroll
        for (int nf = 0; nf < 2; ++nf)
            #pragma unroll
            for (int r = 0; r < 16; ++r) {
                const int mi = a0 + wm*64 + mf*32 + (r & 3) + 8*(r >> 2) + 4*lh;
                const int ni = b0 + wn*64 + nf*32 + l31;
                const u16 v = f2bf(acc[mf][nf][r] * osc);
                if (z < 2) {
                    O[(size_t)mi * PD + ni] = v;
                } else {
                    const int bb_ = ni >> 11, ll = ni & 2047;       // token -> (b, l)
                    Vt[((size_t)(bb_ * 512 + mi)) * 2048 + ll] = v; // mi = h*64+dh
                }
            }
}

// ======================= Flash attention (MFMA) =======================
// Block = (b, h, 128-q tile); 4 waves x 32 q. 64-key tiles.
// S^T = K·Q^T (C col = q -> per-lane softmax state).
// P stays in REGISTERS: S^T C-frag -> PV B-frag needs only an lh-half
// exchange (shfl_xor 32) per reg-quad — no LDS round-trip.
__global__ __launch_bounds__(256) void attn_mfma(
    const u16* __restrict__ Qp, const u16* __restrict__ Kp, const u16* __restrict__ Vt,
    const float* __restrict__ query, float* __restrict__ out)
{
    const int qt = blockIdx.x;   // 0..15
    const int h  = blockIdx.y;   // 0..7
    const int b  = blockIdx.z;   // 0..3
    const int q0 = qt * 128;
    const int L = 2048;

    __shared__ uint4 lds_u4[36864 / 16];
    u16* Ks   = (u16*)lds_u4;            // [64][72] keys x dh
    u16* Vts  = Ks + 64 * 72;            // [64][72] dh x keys
    float* Oe = (float*)lds_u4;          // [128][68] epilogue overlay

    const int tid  = threadIdx.x;
    const int wave = tid >> 6, lane = tid & 63;
    const int l31 = lane & 31, lh = lane >> 5;

    // Q fragments (B-operand): n = q = lane&31, k = dh contiguous
    const int qrow = b * L + q0 + wave * 32 + l31;
    s16x8 qf[4];
    #pragma unroll
    for (int ds = 0; ds < 4; ++ds) {
        uint4 v = *(const uint4*)(Qp + (size_t)qrow * PD + h*64 + ds*16 + lh*8);
        qf[ds] = *(s16x8*)&v;
    }

    f32x16 ot[2];
    #pragma unroll
    for (int mf = 0; mf < 2; ++mf)
        #pragma unroll
        for (int r = 0; r < 16; ++r) ot[mf][r] = 0.f;
    float m_i = -INFINITY, l_i = 0.f;

    const int srow = tid >> 2;          // 0..63
    const int sc   = (tid & 3) * 16;    // 0,16,32,48

    for (int k0 = 0; k0 < L; k0 += 64) {
        __syncthreads();
        {
            const u16* kp = Kp + (size_t)(b*L + k0 + srow) * PD + h*64 + sc;
            const u16* vp = Vt + ((size_t)((b*8 + h)*64 + srow)) * 2048 + k0 + sc;
            uint4 k0v = *(const uint4*)kp;
            uint4 k1v = *(const uint4*)(kp + 8);
            uint4 v0v = *(const uint4*)vp;
            uint4 v1v = *(const uint4*)(vp + 8);
            *(uint4*)&Ks [srow*72 + sc]     = k0v;
            *(uint4*)&Ks [srow*72 + sc + 8] = k1v;
            *(uint4*)&Vts[srow*72 + sc]     = v0v;
            *(uint4*)&Vts[srow*72 + sc + 8] = v1v;
        }
        __syncthreads();

        // S^T = K·Q^T : rows=key, cols=q (scores already in log2 domain via Q scale)
        f32x16 s[2];
        #pragma unroll
        for (int kf = 0; kf < 2; ++kf) {
            #pragma unroll
            for (int r = 0; r < 16; ++r) s[kf][r] = 0.f;
            #pragma unroll
            for (int ds = 0; ds < 4; ++ds) {
                uint4 av = *(uint4*)&Ks[(kf*32 + l31)*72 + ds*16 + lh*8];
                s[kf] = __builtin_amdgcn_mfma_f32_32x32x16_bf16(
                    *(s16x8*)&av, qf[ds], s[kf], 0, 0, 0);
            }
        }

        // online softmax in base-2 domain (q = lane&31)
        float rm = -INFINITY;
        #pragma unroll
        for (int kf = 0; kf < 2; ++kf)
            #pragma unroll
            for (int r = 0; r < 16; ++r) rm = fmaxf(rm, s[kf][r]);
        rm = fmaxf(rm, __shfl_xor(rm, 32));
        const float m_new = fmaxf(m_i, rm);
        const float alpha = exp2f(m_i - m_new);
        float rs = 0.f;
        // P packed bf16 quads: pq[kf][g] covers keys 32kf+8g+4lh+{0..3}
        u32 pq[2][4][2];
        #pragma unroll
        for (int kf = 0; kf < 2; ++kf)
            #pragma unroll
            for (int g = 0; g < 4; ++g) {
                float p0 = exp2f(s[kf][4*g+0] - m_new);
                float p1 = exp2f(s[kf][4*g+1] - m_new);
                float p2 = exp2f(s[kf][4*g+2] - m_new);
                float p3 = exp2f(s[kf][4*g+3] - m_new);
                rs += (p0 + p1) + (p2 + p3);
                pq[kf][g][0] = pk_bf16(p0, p1);
                pq[kf][g][1] = pk_bf16(p2, p3);
            }
        rs += __shfl_xor(rs, 32);
        l_i = l_i * alpha + rs;
        m_i = m_new;
        #pragma unroll
        for (int mf = 0; mf < 2; ++mf)
            #pragma unroll
            for (int r = 0; r < 16; ++r) ot[mf][r] *= alpha;

        // O^T += V^T·P^T. B-frag(kf,t) lane(q,lh) needs keys 32kf+16t+8lh+{0..7}:
        //   j0..3 from lh_src=0's quad g=2t+lh, j4..7 from lh_src=1's same quad.
        //   Own half supplies one; shfl_xor(32) of quad 2t+(lh^1) supplies the other.
        #pragma unroll
        for (int kf = 0; kf < 2; ++kf)
            #pragma unroll
            for (int t = 0; t < 2; ++t) {
                const int g_own  = 2*t + lh;
                const int g_send = 2*t + (lh ^ 1);
                const u32 sx = __shfl_xor((int)pq[kf][g_send][0], 32);
                const u32 sy = __shfl_xor((int)pq[kf][g_send][1], 32);
                const u32 ox = pq[kf][g_own][0], oy = pq[kf][g_own][1];
                union { u32 w[4]; s16x8 v; } bu;
                bu.w[0] = lh ? sx : ox;
                bu.w[1] = lh ? sy : oy;
                bu.w[2] = lh ? ox : sx;
                bu.w[3] = lh ? oy : sy;
                #pragma unroll
                for (int mf = 0; mf < 2; ++mf) {
                    uint4 av = *(uint4*)&Vts[(mf*32 + l31)*72 + kf*32 + t*16 + lh*8];
                    ot[mf] = __builtin_amdgcn_mfma_f32_32x32x16_bf16(
                        *(s16x8*)&av, bu.v, ot[mf], 0, 0, 0);
                }
            }
    }

    // epilogue: O^T (col=q, row=dh) -> LDS transpose -> coalesced fp32 + residual
    __syncthreads();   // all waves done with Ks/Vts before overlay
    const float inv_l = 1.0f / l_i;
    #pragma unroll
    for (int mf = 0; mf < 2; ++mf)
        #pragma unroll
        for (int g = 0; g < 4; ++g) {
            float4 v;
            v.x = ot[mf][g*4+0] * inv_l;
            v.y = ot[mf][g*4+1] * inv_l;
            v.z = ot[mf][g*4+2] * inv_l;
            v.w = ot[mf][g*4+3] * inv_l;
            const int dh0 = mf*32 + 8*g + 4*lh;
            *(float4*)&Oe[(wave*32 + l31)*68 + dh0] = v;
        }
    __syncthreads();
    {
        const int r  = tid >> 1;           // 0..127
        const int c0 = (tid & 1) * 32;
        const size_t gb = ((size_t)(b*L + q0 + r)) * PD + h*64 + c0;
        #pragma unroll
        for (int i = 0; i < 8; ++i) {
            float4 ov = *(float4*)&Oe[r*68 + c0 + 4*i];
            float4 qv = *(const float4*)(query + gb + 4*i);
            ov.x += qv.x; ov.y += qv.y; ov.z += qv.z; ov.w += qv.w;
            *(float4*)(out + gb + 4*i) = ov;
        }
    }
}

// ======================= launch =======================
extern "C" void kernel_launch(void* const* d_in, const int* in_sizes, int n_in,
                              void* d_out, int out_size, void* d_ws, size_t ws_size,
                              hipStream_t stream) {
    const float* query = (const float*)d_in[0];   // [4,2048,512] fp32
    const float* keys  = (const float*)d_in[1];   // [4,2048,512] fp32
    const float* Wq    = (const float*)d_in[2];   // [512,512] fp32
    const float* Wk    = (const float*)d_in[3];
    const float* Wv    = (const float*)d_in[4];
    float* out = (float*)d_out;

    // workspace: Qp,Kp [8192][512] bf16 + Vt [2048][2048] bf16 = 24 MB
    u16* Qp = (u16*)d_ws;
    u16* Kp = Qp + (size_t)8192 * 512;
    u16* Vt = Kp + (size_t)8192 * 512;

    proj_mfma<<<dim3(64, 4, 3), 256, 0, stream>>>(query, keys, Wq, Wk, Wv, Qp, Kp, Vt);
    attn_mfma<<<dim3(16, 8, 4), 256, 0, stream>>>(Qp, Kp, Vt, query, out);
}

// Round 6
// 190.908 us; speedup vs baseline: 1.2819x; 1.2819x over previous
//
#include <hip/hip_runtime.h>
#include <hip/hip_bf16.h>

typedef unsigned short u16;
typedef unsigned int   u32;
typedef short  s16x8  __attribute__((ext_vector_type(8)));
typedef float  f32x16 __attribute__((ext_vector_type(16)));

__device__ __forceinline__ u16 f2bf(float f) {
    union { u32 i; float f; } x; x.f = f;
    u32 r = x.i + 0x7fffu + ((x.i >> 16) & 1u);
    return (u16)(r >> 16);
}
// packed fp32x2 -> bf16x2 (hardware packed cvt on gfx950)
__device__ __forceinline__ u32 pk_bf16(float a, float b) {
    __hip_bfloat162 h = __float22bfloat162_rn(make_float2(a, b));
    union { __hip_bfloat162 h; u32 u; } c; c.h = h; return c.u;
}

#define PD 512

// ======================= Projection GEMM (MFMA) =======================
// z=0: Q = query @ Wq^T -> Qo bf16, pre-scaled by (1/sqrt(512))*log2(e)
// z=1: K = keys  @ Wk^T -> Ko bf16
// z=2: V^T = Wv @ keys^T -> Vt[(b*8+h)*64+dh][2048] bf16
__global__ __launch_bounds__(256) void proj_mfma(
    const float* __restrict__ query, const float* __restrict__ keys,
    const float* __restrict__ Wq, const float* __restrict__ Wk, const float* __restrict__ Wv,
    u16* __restrict__ Qo, u16* __restrict__ Ko, u16* __restrict__ Vt)
{
    const int z = blockIdx.z;
    const float* __restrict__ X = (z == 0) ? query : keys;
    const float* __restrict__ W = (z == 0) ? Wq : ((z == 1) ? Wk : Wv);
    const int bx = blockIdx.x;   // 0..63 token-tile (128)
    const int by = blockIdx.y;   // 0..3  outdim-tile (128)

    const float* __restrict__ Amat = (z < 2) ? X : W;
    const float* __restrict__ Bmat = (z < 2) ? W : X;
    const int a0 = ((z < 2) ? bx : by) * 128;
    const int b0 = ((z < 2) ? by : bx) * 128;

    __shared__ u16 As[128][40];   // [row][k], +8 pad
    __shared__ u16 Bs[128][40];

    const int tid  = threadIdx.x;
    const int wave = tid >> 6, lane = tid & 63;
    const int wm = wave >> 1, wn = wave & 1;
    const int l31 = lane & 31, lh = lane >> 5;

    const int srow = tid >> 1;         // 0..127 staging row
    const int sk   = (tid & 1) * 16;   // 0/16   staging k-offset

    f32x16 acc[2][2];
    #pragma unroll
    for (int i = 0; i < 2; ++i)
        #pragma unroll
        for (int j = 0; j < 2; ++j)
            #pragma unroll
            for (int r = 0; r < 16; ++r) acc[i][j][r] = 0.f;

    for (int k0 = 0; k0 < PD; k0 += 32) {
        __syncthreads();
        {
            const float* ap = Amat + (size_t)(a0 + srow) * PD + k0 + sk;
            const float* bp = Bmat + (size_t)(b0 + srow) * PD + k0 + sk;
            u32 aw[8], bw[8];
            #pragma unroll
            for (int i = 0; i < 4; ++i) {
                float4 av = *(const float4*)(ap + 4*i);
                float4 bv = *(const float4*)(bp + 4*i);
                aw[2*i]   = pk_bf16(av.x, av.y);
                aw[2*i+1] = pk_bf16(av.z, av.w);
                bw[2*i]   = pk_bf16(bv.x, bv.y);
                bw[2*i+1] = pk_bf16(bv.z, bv.w);
            }
            *(uint4*)&As[srow][sk]     = *(uint4*)&aw[0];
            *(uint4*)&As[srow][sk + 8] = *(uint4*)&aw[4];
            *(uint4*)&Bs[srow][sk]     = *(uint4*)&bw[0];
            *(uint4*)&Bs[srow][sk + 8] = *(uint4*)&bw[4];
        }
        __syncthreads();

        #pragma unroll
        for (int ks = 0; ks < 2; ++ks) {
            s16x8 af[2], bfr[2];
            #pragma unroll
            for (int mf = 0; mf < 2; ++mf) {
                uint4 v = *(uint4*)&As[wm*64 + mf*32 + l31][ks*16 + lh*8];
                af[mf] = *(s16x8*)&v;
            }
            #pragma unroll
            for (int nf = 0; nf < 2; ++nf) {
                uint4 v = *(uint4*)&Bs[wn*64 + nf*32 + l31][ks*16 + lh*8];
                bfr[nf] = *(s16x8*)&v;
            }
            #pragma unroll
            for (int mf = 0; mf < 2; ++mf)
                #pragma unroll
                for (int nf = 0; nf < 2; ++nf)
                    acc[mf][nf] = __builtin_amdgcn_mfma_f32_32x32x16_bf16(
                        af[mf], bfr[nf], acc[mf][nf], 0, 0, 0);
        }
    }

    // C/D layout: col=lane&31, row=(reg&3)+8*(reg>>2)+4*(lane>>5)
    // Q gets (1/sqrt(512)) * log2(e): softmax runs in base-2 domain.
    const float osc = (z == 0) ? (0.044194173824159216f * 1.4426950408889634f) : 1.0f;
    u16* __restrict__ O = (z == 0) ? Qo : Ko;
    #pragma unroll
    for (int mf = 0; mf < 2; ++mf)
        #pragma unroll
        for (int nf = 0; nf < 2; ++nf)
            #pragma unroll
            for (int r = 0; r < 16; ++r) {
                const int mi = a0 + wm*64 + mf*32 + (r & 3) + 8*(r >> 2) + 4*lh;
                const int ni = b0 + wn*64 + nf*32 + l31;
                const u16 v = f2bf(acc[mf][nf][r] * osc);
                if (z < 2) {
                    O[(size_t)mi * PD + ni] = v;
                } else {
                    const int bb_ = ni >> 11, ll = ni & 2047;       // token -> (b, l)
                    Vt[((size_t)(bb_ * 512 + mi)) * 2048 + ll] = v; // mi = h*64+dh
                }
            }
}

// ======================= Flash attention (MFMA) =======================
// Block = (b, h, 128-q tile); 4 waves x 32 q. 64-key tiles.
// S^T = K·Q^T (C col = q -> per-lane softmax state). P goes through a
// wave-private LDS round-trip (R3 structure — measured faster than
// shfl-based register exchange, which doubled VALU work in R4).
__global__ __launch_bounds__(256) void attn_mfma(
    const u16* __restrict__ Qp, const u16* __restrict__ Kp, const u16* __restrict__ Vt,
    const float* __restrict__ query, float* __restrict__ out)
{
    const int qt = blockIdx.x;   // 0..15
    const int h  = blockIdx.y;   // 0..7
    const int b  = blockIdx.z;   // 0..3
    const int q0 = qt * 128;
    const int L = 2048;

    __shared__ uint4 lds_u4[36864 / 16];
    u16* Ks   = (u16*)lds_u4;            // [64][72] keys x dh
    u16* Vts  = Ks + 64 * 72;            // [64][72] dh x keys
    u16* P2a  = Vts + 64 * 72;           // [4][32][72] per-wave P (q x key)
    float* Oe = (float*)lds_u4;          // [128][68] epilogue overlay

    const int tid  = threadIdx.x;
    const int wave = tid >> 6, lane = tid & 63;
    const int l31 = lane & 31, lh = lane >> 5;
    u16* P2 = P2a + wave * 32 * 72;

    // Q fragments (B-operand): n = q = lane&31, k = dh contiguous
    const int qrow = b * L + q0 + wave * 32 + l31;
    s16x8 qf[4];
    #pragma unroll
    for (int ds = 0; ds < 4; ++ds) {
        uint4 v = *(const uint4*)(Qp + (size_t)qrow * PD + h*64 + ds*16 + lh*8);
        qf[ds] = *(s16x8*)&v;
    }

    f32x16 ot[2];
    #pragma unroll
    for (int mf = 0; mf < 2; ++mf)
        #pragma unroll
        for (int r = 0; r < 16; ++r) ot[mf][r] = 0.f;
    float m_i = -INFINITY, l_i = 0.f;

    const int srow = tid >> 2;          // 0..63
    const int sc   = (tid & 3) * 16;    // 0,16,32,48

    for (int k0 = 0; k0 < L; k0 += 64) {
        __syncthreads();
        {
            const u16* kp = Kp + (size_t)(b*L + k0 + srow) * PD + h*64 + sc;
            const u16* vp = Vt + ((size_t)((b*8 + h)*64 + srow)) * 2048 + k0 + sc;
            uint4 k0v = *(const uint4*)kp;
            uint4 k1v = *(const uint4*)(kp + 8);
            uint4 v0v = *(const uint4*)vp;
            uint4 v1v = *(const uint4*)(vp + 8);
            *(uint4*)&Ks [srow*72 + sc]     = k0v;
            *(uint4*)&Ks [srow*72 + sc + 8] = k1v;
            *(uint4*)&Vts[srow*72 + sc]     = v0v;
            *(uint4*)&Vts[srow*72 + sc + 8] = v1v;
        }
        __syncthreads();

        // S^T = K·Q^T : rows=key, cols=q (scores in log2 domain via Q scale)
        f32x16 s[2];
        #pragma unroll
        for (int kf = 0; kf < 2; ++kf) {
            #pragma unroll
            for (int r = 0; r < 16; ++r) s[kf][r] = 0.f;
            #pragma unroll
            for (int ds = 0; ds < 4; ++ds) {
                uint4 av = *(uint4*)&Ks[(kf*32 + l31)*72 + ds*16 + lh*8];
                s[kf] = __builtin_amdgcn_mfma_f32_32x32x16_bf16(
                    *(s16x8*)&av, qf[ds], s[kf], 0, 0, 0);
            }
        }

        // online softmax in base-2 domain (q = lane&31)
        float rm = -INFINITY;
        #pragma unroll
        for (int kf = 0; kf < 2; ++kf)
            #pragma unroll
            for (int r = 0; r < 16; ++r) rm = fmaxf(rm, s[kf][r]);
        rm = fmaxf(rm, __shfl_xor(rm, 32));
        const float m_new = fmaxf(m_i, rm);
        const float alpha = exp2f(m_i - m_new);
        float rs = 0.f;
        // P -> LDS: P2[q][key], key=(reg&3)+8*(reg>>2)+4*lh+32*kf
        #pragma unroll
        for (int kf = 0; kf < 2; ++kf)
            #pragma unroll
            for (int g = 0; g < 4; ++g) {
                float p0 = exp2f(s[kf][4*g+0] - m_new);
                float p1 = exp2f(s[kf][4*g+1] - m_new);
                float p2 = exp2f(s[kf][4*g+2] - m_new);
                float p3 = exp2f(s[kf][4*g+3] - m_new);
                rs += (p0 + p1) + (p2 + p3);
                uint2 w2;
                w2.x = pk_bf16(p0, p1);
                w2.y = pk_bf16(p2, p3);
                *(uint2*)&P2[l31*72 + kf*32 + g*8 + lh*4] = w2;
            }
        rs += __shfl_xor(rs, 32);
        l_i = l_i * alpha + rs;
        m_i = m_new;
        #pragma unroll
        for (int mf = 0; mf < 2; ++mf)
            #pragma unroll
            for (int r = 0; r < 16; ++r) ot[mf][r] *= alpha;
        // (wave-private P2: in-wave lgkmcnt ordering suffices, no barrier)

        // O^T += V^T · P^T : A = Vts rows (dh), B = P2 rows (q), contract key
        #pragma unroll
        for (int ks = 0; ks < 4; ++ks) {
            uint4 bv = *(uint4*)&P2[l31*72 + ks*16 + lh*8];
            s16x8 bfr = *(s16x8*)&bv;
            #pragma unroll
            for (int mf = 0; mf < 2; ++mf) {
                uint4 av = *(uint4*)&Vts[(mf*32 + l31)*72 + ks*16 + lh*8];
                ot[mf] = __builtin_amdgcn_mfma_f32_32x32x16_bf16(
                    *(s16x8*)&av, bfr, ot[mf], 0, 0, 0);
            }
        }
    }

    // epilogue: O^T (col=q, row=dh) -> LDS transpose -> coalesced fp32 + residual
    __syncthreads();   // all waves done with Ks/Vts/P2 before overlay
    const float inv_l = 1.0f / l_i;
    #pragma unroll
    for (int mf = 0; mf < 2; ++mf)
        #pragma unroll
        for (int g = 0; g < 4; ++g) {
            float4 v;
            v.x = ot[mf][g*4+0] * inv_l;
            v.y = ot[mf][g*4+1] * inv_l;
            v.z = ot[mf][g*4+2] * inv_l;
            v.w = ot[mf][g*4+3] * inv_l;
            const int dh0 = mf*32 + 8*g + 4*lh;
            *(float4*)&Oe[(wave*32 + l31)*68 + dh0] = v;
        }
    __syncthreads();
    {
        const int r  = tid >> 1;           // 0..127
        const int c0 = (tid & 1) * 32;
        const size_t gb = ((size_t)(b*L + q0 + r)) * PD + h*64 + c0;
        #pragma unroll
        for (int i = 0; i < 8; ++i) {
            float4 ov = *(float4*)&Oe[r*68 + c0 + 4*i];
            float4 qv = *(const float4*)(query + gb + 4*i);
            ov.x += qv.x; ov.y += qv.y; ov.z += qv.z; ov.w += qv.w;
            *(float4*)(out + gb + 4*i) = ov;
        }
    }
}

// ======================= launch =======================
extern "C" void kernel_launch(void* const* d_in, const int* in_sizes, int n_in,
                              void* d_out, int out_size, void* d_ws, size_t ws_size,
                              hipStream_t stream) {
    const float* query = (const float*)d_in[0];   // [4,2048,512] fp32
    const float* keys  = (const float*)d_in[1];   // [4,2048,512] fp32
    const float* Wq    = (const float*)d_in[2];   // [512,512] fp32
    const float* Wk    = (const float*)d_in[3];
    const float* Wv    = (const float*)d_in[4];
    float* out = (float*)d_out;

    // workspace: Qp,Kp [8192][512] bf16 + Vt [2048][2048] bf16 = 24 MB
    u16* Qp = (u16*)d_ws;
    u16* Kp = Qp + (size_t)8192 * 512;
    u16* Vt = Kp + (size_t)8192 * 512;

    proj_mfma<<<dim3(64, 4, 3), 256, 0, stream>>>(query, keys, Wq, Wk, Wv, Qp, Kp, Vt);
    attn_mfma<<<dim3(16, 8, 4), 256, 0, stream>>>(Qp, Kp, Vt, query, out);
}

// Round 7
// 177.880 us; speedup vs baseline: 1.3757x; 1.0732x over previous
//
#include <hip/hip_runtime.h>

typedef unsigned short u16;
typedef unsigned int   u32;
typedef short  s16x8  __attribute__((ext_vector_type(8)));
typedef float  f32x16 __attribute__((ext_vector_type(16)));

// fp32 -> bf16 (round-half-up) single value
__device__ __forceinline__ u16 f2bf(float f) {
    union { u32 i; float f; } x; x.f = f;
    return (u16)((x.i + 0x8000u) >> 16);
}
// pack two fp32 -> bf16x2 (round-half-up): 2 adds + 1 v_perm_b32
__device__ __forceinline__ u32 pk_hi16(float a, float b) {
    union { float f; u32 u; } ua, ub; ua.f = a; ub.f = b;
    return __builtin_amdgcn_perm(ub.u + 0x8000u, ua.u + 0x8000u, 0x07060302u);
}

#define PD 512

// ======================= Projection GEMM (MFMA, pipelined) =======================
// z=0: Q = query @ Wq^T -> Qo bf16, pre-scaled by (1/sqrt(512))*log2(e)
// z=1: K = keys  @ Wk^T -> Ko bf16
// z=2: V^T = Wv @ keys^T -> Vt[(b*8+h)*64+dh][2048] bf16
__global__ __launch_bounds__(256) void proj_mfma(
    const float* __restrict__ query, const float* __restrict__ keys,
    const float* __restrict__ Wq, const float* __restrict__ Wk, const float* __restrict__ Wv,
    u16* __restrict__ Qo, u16* __restrict__ Ko, u16* __restrict__ Vt)
{
    const int z = blockIdx.z;
    const float* __restrict__ X = (z == 0) ? query : keys;
    const float* __restrict__ W = (z == 0) ? Wq : ((z == 1) ? Wk : Wv);
    const int bx = blockIdx.x;   // 0..63 token-tile (128)
    const int by = blockIdx.y;   // 0..3  outdim-tile (128)

    const float* __restrict__ Amat = (z < 2) ? X : W;
    const float* __restrict__ Bmat = (z < 2) ? W : X;
    const int a0 = ((z < 2) ? bx : by) * 128;
    const int b0 = ((z < 2) ? by : bx) * 128;

    __shared__ u16 As[128][40];   // [row][k], +8 pad
    __shared__ u16 Bs[128][40];

    const int tid  = threadIdx.x;
    const int wave = tid >> 6, lane = tid & 63;
    const int wm = wave >> 1, wn = wave & 1;
    const int l31 = lane & 31, lh = lane >> 5;

    const int srow = tid >> 1;         // 0..127 staging row
    const int sk   = (tid & 1) * 16;   // 0/16   staging k-offset

    f32x16 acc[2][2];
    #pragma unroll
    for (int i = 0; i < 2; ++i)
        #pragma unroll
        for (int j = 0; j < 2; ++j)
            #pragma unroll
            for (int r = 0; r < 16; ++r) acc[i][j][r] = 0.f;

    // prologue: prefetch k0 = 0
    float4 ra[4], rb[4];
    {
        const float* ap = Amat + (size_t)(a0 + srow) * PD + sk;
        const float* bp = Bmat + (size_t)(b0 + srow) * PD + sk;
        #pragma unroll
        for (int i = 0; i < 4; ++i) {
            ra[i] = *(const float4*)(ap + 4*i);
            rb[i] = *(const float4*)(bp + 4*i);
        }
    }

    for (int k0 = 0; k0 < PD; k0 += 32) {
        __syncthreads();
        {
            u32 aw[8], bw[8];
            #pragma unroll
            for (int i = 0; i < 4; ++i) {
                aw[2*i]   = pk_hi16(ra[i].x, ra[i].y);
                aw[2*i+1] = pk_hi16(ra[i].z, ra[i].w);
                bw[2*i]   = pk_hi16(rb[i].x, rb[i].y);
                bw[2*i+1] = pk_hi16(rb[i].z, rb[i].w);
            }
            *(uint4*)&As[srow][sk]     = *(uint4*)&aw[0];
            *(uint4*)&As[srow][sk + 8] = *(uint4*)&aw[4];
            *(uint4*)&Bs[srow][sk]     = *(uint4*)&bw[0];
            *(uint4*)&Bs[srow][sk + 8] = *(uint4*)&bw[4];
        }
        // prefetch next k-slab: in flight across barrier + MFMA phase
        if (k0 + 32 < PD) {
            const float* ap = Amat + (size_t)(a0 + srow) * PD + (k0 + 32) + sk;
            const float* bp = Bmat + (size_t)(b0 + srow) * PD + (k0 + 32) + sk;
            #pragma unroll
            for (int i = 0; i < 4; ++i) {
                ra[i] = *(const float4*)(ap + 4*i);
                rb[i] = *(const float4*)(bp + 4*i);
            }
        }
        __syncthreads();

        #pragma unroll
        for (int ks = 0; ks < 2; ++ks) {
            s16x8 af[2], bfr[2];
            #pragma unroll
            for (int mf = 0; mf < 2; ++mf) {
                uint4 v = *(uint4*)&As[wm*64 + mf*32 + l31][ks*16 + lh*8];
                af[mf] = *(s16x8*)&v;
            }
            #pragma unroll
            for (int nf = 0; nf < 2; ++nf) {
                uint4 v = *(uint4*)&Bs[wn*64 + nf*32 + l31][ks*16 + lh*8];
                bfr[nf] = *(s16x8*)&v;
            }
            #pragma unroll
            for (int mf = 0; mf < 2; ++mf)
                #pragma unroll
                for (int nf = 0; nf < 2; ++nf)
                    acc[mf][nf] = __builtin_amdgcn_mfma_f32_32x32x16_bf16(
                        af[mf], bfr[nf], acc[mf][nf], 0, 0, 0);
        }
    }

    // C/D layout: col=lane&31, row=(reg&3)+8*(reg>>2)+4*(lane>>5)
    // Q gets (1/sqrt(512)) * log2(e): softmax runs in base-2 domain.
    const float osc = (z == 0) ? (0.044194173824159216f * 1.4426950408889634f) : 1.0f;
    u16* __restrict__ O = (z == 0) ? Qo : Ko;
    #pragma unroll
    for (int mf = 0; mf < 2; ++mf)
        #pragma unroll
        for (int nf = 0; nf < 2; ++nf)
            #pragma unroll
            for (int r = 0; r < 16; ++r) {
                const int mi = a0 + wm*64 + mf*32 + (r & 3) + 8*(r >> 2) + 4*lh;
                const int ni = b0 + wn*64 + nf*32 + l31;
                const u16 v = f2bf(acc[mf][nf][r] * osc);
                if (z < 2) {
                    O[(size_t)mi * PD + ni] = v;
                } else {
                    const int bb_ = ni >> 11, ll = ni & 2047;       // token -> (b, l)
                    Vt[((size_t)(bb_ * 512 + mi)) * 2048 + ll] = v; // mi = h*64+dh
                }
            }
}

// ======================= Flash attention (MFMA, pipelined) =======================
// Block = (b, h, 128-q tile); 4 waves x 32 q. 64-key tiles.
// S^T = K·Q^T (C col = q -> per-lane softmax state). P via wave-private
// LDS round-trip (R3-proven). K/V tile t+1 prefetched into registers
// during compute of tile t — global latency hidden, no vmcnt(0) stall.
__global__ __launch_bounds__(256) void attn_mfma(
    const u16* __restrict__ Qp, const u16* __restrict__ Kp, const u16* __restrict__ Vt,
    const float* __restrict__ query, float* __restrict__ out)
{
    const int qt = blockIdx.x;   // 0..15
    const int h  = blockIdx.y;   // 0..7
    const int b  = blockIdx.z;   // 0..3
    const int q0 = qt * 128;
    const int L = 2048;

    __shared__ uint4 lds_u4[36864 / 16];
    u16* Ks   = (u16*)lds_u4;            // [64][72] keys x dh
    u16* Vts  = Ks + 64 * 72;            // [64][72] dh x keys
    u16* P2a  = Vts + 64 * 72;           // [4][32][72] per-wave P (q x key)
    float* Oe = (float*)lds_u4;          // [128][68] epilogue overlay

    const int tid  = threadIdx.x;
    const int wave = tid >> 6, lane = tid & 63;
    const int l31 = lane & 31, lh = lane >> 5;
    u16* P2 = P2a + wave * 32 * 72;

    // Q fragments (B-operand): n = q = lane&31, k = dh contiguous
    const int qrow = b * L + q0 + wave * 32 + l31;
    s16x8 qf[4];
    #pragma unroll
    for (int ds = 0; ds < 4; ++ds) {
        uint4 v = *(const uint4*)(Qp + (size_t)qrow * PD + h*64 + ds*16 + lh*8);
        qf[ds] = *(s16x8*)&v;
    }

    f32x16 ot[2];
    #pragma unroll
    for (int mf = 0; mf < 2; ++mf)
        #pragma unroll
        for (int r = 0; r < 16; ++r) ot[mf][r] = 0.f;
    float m_i = -INFINITY, l_i = 0.f;

    const int srow = tid >> 2;          // 0..63
    const int sc   = (tid & 3) * 16;    // 0,16,32,48

    // prologue: prefetch K/V tile 0
    uint4 rk0, rk1, rv0, rv1;
    {
        const u16* kp = Kp + (size_t)(b*L + srow) * PD + h*64 + sc;
        const u16* vp = Vt + ((size_t)((b*8 + h)*64 + srow)) * 2048 + sc;
        rk0 = *(const uint4*)kp;      rk1 = *(const uint4*)(kp + 8);
        rv0 = *(const uint4*)vp;      rv1 = *(const uint4*)(vp + 8);
    }

    for (int k0 = 0; k0 < L; k0 += 64) {
        __syncthreads();
        *(uint4*)&Ks [srow*72 + sc]     = rk0;
        *(uint4*)&Ks [srow*72 + sc + 8] = rk1;
        *(uint4*)&Vts[srow*72 + sc]     = rv0;
        *(uint4*)&Vts[srow*72 + sc + 8] = rv1;
        if (k0 + 64 < L) {   // prefetch next tile; in flight across compute
            const u16* kp = Kp + (size_t)(b*L + (k0+64) + srow) * PD + h*64 + sc;
            const u16* vp = Vt + ((size_t)((b*8 + h)*64 + srow)) * 2048 + (k0+64) + sc;
            rk0 = *(const uint4*)kp;  rk1 = *(const uint4*)(kp + 8);
            rv0 = *(const uint4*)vp;  rv1 = *(const uint4*)(vp + 8);
        }
        __syncthreads();

        // S^T = K·Q^T : rows=key, cols=q (scores in log2 domain via Q scale)
        f32x16 s[2];
        #pragma unroll
        for (int kf = 0; kf < 2; ++kf) {
            #pragma unroll
            for (int r = 0; r < 16; ++r) s[kf][r] = 0.f;
            #pragma unroll
            for (int ds = 0; ds < 4; ++ds) {
                uint4 av = *(uint4*)&Ks[(kf*32 + l31)*72 + ds*16 + lh*8];
                s[kf] = __builtin_amdgcn_mfma_f32_32x32x16_bf16(
                    *(s16x8*)&av, qf[ds], s[kf], 0, 0, 0);
            }
        }

        // online softmax in base-2 domain (q = lane&31)
        float rm = -INFINITY;
        #pragma unroll
        for (int kf = 0; kf < 2; ++kf)
            #pragma unroll
            for (int r = 0; r < 16; ++r) rm = fmaxf(rm, s[kf][r]);
        rm = fmaxf(rm, __shfl_xor(rm, 32));
        const float m_new = fmaxf(m_i, rm);
        const float alpha = __builtin_amdgcn_exp2f(m_i - m_new);
        float rs = 0.f;
        // P -> LDS: P2[q][key], key=(reg&3)+8*(reg>>2)+4*lh+32*kf
        #pragma unroll
        for (int kf = 0; kf < 2; ++kf)
            #pragma unroll
            for (int g = 0; g < 4; ++g) {
                float p0 = __builtin_amdgcn_exp2f(s[kf][4*g+0] - m_new);
                float p1 = __builtin_amdgcn_exp2f(s[kf][4*g+1] - m_new);
                float p2 = __builtin_amdgcn_exp2f(s[kf][4*g+2] - m_new);
                float p3 = __builtin_amdgcn_exp2f(s[kf][4*g+3] - m_new);
                rs += (p0 + p1) + (p2 + p3);
                uint2 w2;
                w2.x = pk_hi16(p0, p1);
                w2.y = pk_hi16(p2, p3);
                *(uint2*)&P2[l31*72 + kf*32 + g*8 + lh*4] = w2;
            }
        rs += __shfl_xor(rs, 32);
        l_i = l_i * alpha + rs;
        m_i = m_new;
        #pragma unroll
        for (int mf = 0; mf < 2; ++mf)
            #pragma unroll
            for (int r = 0; r < 16; ++r) ot[mf][r] *= alpha;
        // (wave-private P2: in-wave lgkmcnt ordering suffices, no barrier)

        // O^T += V^T · P^T : A = Vts rows (dh), B = P2 rows (q), contract key
        #pragma unroll
        for (int ks = 0; ks < 4; ++ks) {
            uint4 bv = *(uint4*)&P2[l31*72 + ks*16 + lh*8];
            s16x8 bfr = *(s16x8*)&bv;
            #pragma unroll
            for (int mf = 0; mf < 2; ++mf) {
                uint4 av = *(uint4*)&Vts[(mf*32 + l31)*72 + ks*16 + lh*8];
                ot[mf] = __builtin_amdgcn_mfma_f32_32x32x16_bf16(
                    *(s16x8*)&av, bfr, ot[mf], 0, 0, 0);
            }
        }
    }

    // epilogue: O^T (col=q, row=dh) -> LDS transpose -> coalesced fp32 + residual
    __syncthreads();   // all waves done with Ks/Vts/P2 before overlay
    const float inv_l = 1.0f / l_i;
    #pragma unroll
    for (int mf = 0; mf < 2; ++mf)
        #pragma unroll
        for (int g = 0; g < 4; ++g) {
            float4 v;
            v.x = ot[mf][g*4+0] * inv_l;
            v.y = ot[mf][g*4+1] * inv_l;
            v.z = ot[mf][g*4+2] * inv_l;
            v.w = ot[mf][g*4+3] * inv_l;
            const int dh0 = mf*32 + 8*g + 4*lh;
            *(float4*)&Oe[(wave*32 + l31)*68 + dh0] = v;
        }
    __syncthreads();
    {
        const int r  = tid >> 1;           // 0..127
        const int c0 = (tid & 1) * 32;
        const size_t gb = ((size_t)(b*L + q0 + r)) * PD + h*64 + c0;
        #pragma unroll
        for (int i = 0; i < 8; ++i) {
            float4 ov = *(float4*)&Oe[r*68 + c0 + 4*i];
            float4 qv = *(const float4*)(query + gb + 4*i);
            ov.x += qv.x; ov.y += qv.y; ov.z += qv.z; ov.w += qv.w;
            *(float4*)(out + gb + 4*i) = ov;
        }
    }
}

// ======================= launch =======================
extern "C" void kernel_launch(void* const* d_in, const int* in_sizes, int n_in,
                              void* d_out, int out_size, void* d_ws, size_t ws_size,
                              hipStream_t stream) {
    const float* query = (const float*)d_in[0];   // [4,2048,512] fp32
    const float* keys  = (const float*)d_in[1];   // [4,2048,512] fp32
    const float* Wq    = (const float*)d_in[2];   // [512,512] fp32
    const float* Wk    = (const float*)d_in[3];
    const float* Wv    = (const float*)d_in[4];
    float* out = (float*)d_out;

    // workspace: Qp,Kp [8192][512] bf16 + Vt [2048][2048] bf16 = 24 MB
    u16* Qp = (u16*)d_ws;
    u16* Kp = Qp + (size_t)8192 * 512;
    u16* Vt = Kp + (size_t)8192 * 512;

    proj_mfma<<<dim3(64, 4, 3), 256, 0, stream>>>(query, keys, Wq, Wk, Wv, Qp, Kp, Vt);
    attn_mfma<<<dim3(16, 8, 4), 256, 0, stream>>>(Qp, Kp, Vt, query, out);
}